// Round 6
// baseline (214.534 us; speedup 1.0000x reference)
//
#include <hip/hip_runtime.h>

// FWEnergyGAD: element-wise double-well energy + forces + GAD direction +
// 2x2 Hessian eigendecomposition (closed form).
//
// Outputs concatenated flat in return order (n = B):
//   [0,     n)   energy
//   [n,    3n)   forces      (B,2)
//   [3n,   5n)   energy_grad (B,2)
//   [5n,   9n)   hessian     (B,2,2)
//   [9n,  10n)   eigenval 0  (smaller)
//   [10n, 11n)   eigenval 1  (larger)
//
// v7: OUTPUT-MAJOR flat decomposition. Six point-major variants (v1-v6:
// ILP, burst size, NT, native math, persistence) all land at 88-97us for
// 218 MB (~2.45 TB/s) while the harness fill hits 6.7 TB/s in the same
// timed region. The one property all six shared: every wave writes 6
// far-apart output streams concurrently -> chip-wide HBM sees 6
// interleaved write streams. The fill writes ONE. v7: each thread owns 4
// contiguous floats of the FLAT output and recomputes the needed
// per-point values (~30 flops, free). Region boundaries are block-aligned
// (n/4 divisible by 256) -> no divergence. Only ~2048 of 45056 blocks are
// resident at once -> execution sweeps the output in address order: 1-2
// contiguous write streams at any instant, fill-shaped. Input re-read per
// region is L3-served (33.5 MB, re-touched within <100 MB of traffic).

typedef float f2v __attribute__((ext_vector_type(2)));
typedef float f4v __attribute__((ext_vector_type(4)));

namespace {

struct P { float u, v, uu, vv, a, b; };

__device__ __forceinline__ P pre(float px, float py) {
    P o;
    o.u = px - 0.5f;
    o.v = py - 0.5f;
    o.uu = o.u * o.u;
    o.vv = o.v * o.v;
    o.a = o.uu - 1.0f;
    o.b = o.vv - 1.0f;
    return o;
}

__device__ __forceinline__ float energyf(const P& p) {
    return p.a * p.a + p.b * p.b + 0.1f * p.u * p.v;
}

__device__ __forceinline__ f2v forcef(const P& p) {
    f2v f;
    f.x = -(4.0f * p.u * p.a + 0.1f * p.v);
    f.y = -(4.0f * p.v * p.b + 0.1f * p.u);
    return f;
}

__device__ __forceinline__ f2v eigf(const P& p) {   // (l0, l1)
    float hxx = 12.0f * p.uu - 4.0f;
    float hyy = 12.0f * p.vv - 4.0f;
    float d = 0.5f * (hxx - hyy);
    float m = 0.5f * (hxx + hyy);
    float r = __builtin_amdgcn_sqrtf(d * d + 0.01f);   // r >= 0.1
    f2v e; e.x = m - r; e.y = m + r;
    return e;
}

__device__ __forceinline__ f2v gradf(const P& p) {
    float hxx = 12.0f * p.uu - 4.0f;
    float hyy = 12.0f * p.vv - 4.0f;
    float d = 0.5f * (hxx - hyy);
    float m = 0.5f * (hxx + hyy);
    float r = __builtin_amdgcn_sqrtf(d * d + 0.01f);
    float l0 = m - r, l1 = m + r;
    f2v f = forcef(p);
    // Eigenvector branch chosen to avoid fp32 cancellation (|d| up to ~380
    // vs hxy = 0.1; the wrong branch computes r-|d|).
    bool pos = (d >= 0.0f);
    float wx = pos ? 0.1f : (d - r);
    float wy = pos ? -(d + r) : 0.1f;
    float n2 = wx * wx + wy * wy;            // >= 0.01
    float fd = f.x * wx + f.y * wy;
    float s = (2.0f * fd) * __builtin_amdgcn_rcpf(n2);
    float gx = -f.x + s * wx;
    float gy = -f.y + s * wy;
    float g2 = gx * gx + gy * gy;            // gmag^2; gmag<1 <=> g2<1
    if (l0 * l1 > 0.0f && g2 < 1.0f) {
        float inv = __builtin_amdgcn_rsqf(fmaxf(g2, 1e-60f));
        gx *= inv;
        gy *= inv;
    }
    // TAU = 1.0 -> energy_grad == gad
    f2v g; g.x = gx; g.y = gy;
    return g;
}

}  // namespace

// Fast path: n % 4 == 0. One thread per float4 of the flat output.
__global__ __launch_bounds__(256) void fw_flat_kernel(
    const float* __restrict__ in, float* __restrict__ out, int n) {
    const float BETA = 0.1f;
    size_t n4 = (size_t)(n >> 2);            // float4s per n-float stream
    size_t q = (size_t)blockIdx.x * blockDim.x + threadIdx.x;
    if (q >= 11 * n4) return;

    const f2v* in2 = (const f2v*)in;
    const f4v* in4 = (const f4v*)in;
    f4v res;

    if (q < n4) {
        // energy: 4 points per float4
        size_t t = q;
        f4v A = in4[2 * t], B = in4[2 * t + 1];
        res.x = energyf(pre(A.x, A.y));
        res.y = energyf(pre(A.z, A.w));
        res.z = energyf(pre(B.x, B.y));
        res.w = energyf(pre(B.z, B.w));
    } else if (q < 3 * n4) {
        // forces: 2 points per float4
        size_t t = q - n4;
        f4v A = in4[t];
        f2v f0 = forcef(pre(A.x, A.y));
        f2v f1 = forcef(pre(A.z, A.w));
        res.x = f0.x; res.y = f0.y; res.z = f1.x; res.w = f1.y;
    } else if (q < 5 * n4) {
        // energy_grad: 2 points per float4 (full pipeline)
        size_t t = q - 3 * n4;
        f4v A = in4[t];
        f2v g0 = gradf(pre(A.x, A.y));
        f2v g1 = gradf(pre(A.z, A.w));
        res.x = g0.x; res.y = g0.y; res.z = g1.x; res.w = g1.y;
    } else if (q < 9 * n4) {
        // hessian: 1 point per float4
        size_t t = q - 5 * n4;
        f2v p = in2[t];
        P pp = pre(p.x, p.y);
        res.x = 12.0f * pp.uu - 4.0f;
        res.y = BETA;
        res.z = BETA;
        res.w = 12.0f * pp.vv - 4.0f;
    } else if (q < 10 * n4) {
        // eigenval 0: 4 points per float4
        size_t t = q - 9 * n4;
        f4v A = in4[2 * t], B = in4[2 * t + 1];
        res.x = eigf(pre(A.x, A.y)).x;
        res.y = eigf(pre(A.z, A.w)).x;
        res.z = eigf(pre(B.x, B.y)).x;
        res.w = eigf(pre(B.z, B.w)).x;
    } else {
        // eigenval 1: 4 points per float4
        size_t t = q - 10 * n4;
        f4v A = in4[2 * t], B = in4[2 * t + 1];
        res.x = eigf(pre(A.x, A.y)).y;
        res.y = eigf(pre(A.z, A.w)).y;
        res.z = eigf(pre(B.x, B.y)).y;
        res.w = eigf(pre(B.z, B.w)).y;
    }

    ((f4v*)out)[q] = res;
}

// Fallback (n % 4 != 0): v4 point-major scalar kernel, known-correct.
__global__ __launch_bounds__(256) void fw_energy_gad_scalar(
    const f2v* __restrict__ in, float* __restrict__ out, int n) {
    int i = blockIdx.x * blockDim.x + threadIdx.x;
    if (i >= n) return;
    const float BETA = 0.1f;
    f2v pt = in[i];
    P p = pre(pt.x, pt.y);
    float energy = energyf(p);
    f2v f = forcef(p);
    f2v e = eigf(p);
    f2v g = gradf(p);
    size_t N = (size_t)n;
    out[i] = energy;
    ((f2v*)(out + N))[i] = f;
    ((f2v*)(out + 3 * N))[i] = g;
    f4v ho; ho.x = 12.0f * p.uu - 4.0f; ho.y = BETA; ho.z = BETA;
    ho.w = 12.0f * p.vv - 4.0f;
    ((f4v*)(out + 5 * N))[i] = ho;
    out[9 * N + i] = e.x;
    out[10 * N + i] = e.y;
}

extern "C" void kernel_launch(void* const* d_in, const int* in_sizes, int n_in,
                              void* d_out, int out_size, void* d_ws, size_t ws_size,
                              hipStream_t stream) {
    const float* in = (const float*)d_in[0];
    float* out = (float*)d_out;
    int n = in_sizes[0] / 2;   // B points, each (x, y)

    if ((n & 3) == 0) {
        size_t total = 11 * (size_t)(n >> 2);      // float4s in flat output
        int block = 256;
        int grid = (int)((total + block - 1) / block);
        fw_flat_kernel<<<grid, block, 0, stream>>>(in, out, n);
    } else {
        int block = 256;
        int grid = (n + block - 1) / block;
        fw_energy_gad_scalar<<<grid, block, 0, stream>>>((const f2v*)in, out, n);
    }
}

// Round 9
// 201.590 us; speedup vs baseline: 1.0642x; 1.0642x over previous
//
#include <hip/hip_runtime.h>

// FWEnergyGAD: element-wise double-well energy + forces + GAD direction +
// 2x2 Hessian eigendecomposition (closed form).
//
// Outputs concatenated flat in return order (n = B):
//   [0,     n)   energy
//   [n,    3n)   forces      (B,2)
//   [3n,   5n)   energy_grad (B,2)
//   [5n,   9n)   hessian     (B,2,2)
//   [9n,  10n)   eigenval 0  (smaller)
//   [10n, 11n)   eigenval 1  (larger)
//
// v8c: PHASE-SEPARATED reads/writes, minimal single-kernel form (rounds 7
// and 8 died on container acquisition before running; this shrinks attack
// surface: one kernel, unconditional launch, uniform bounds guards, no
// fallback path). The experiment is unchanged:
// Seven measured variants (v1-v7: ILP, burst size, NT, native math,
// persistence, single-stream output-major) all land at 88-104us kernel
// (~2.4 TB/s eff) while the harness's pure-WRITE fill hits 6.7 TB/s in the
// same timed region. All seven interleave input reads with output writes
// finely in time, chip-wide -> HBM read/write bus turnaround. v8 isolates
// that: input (33.5 MB) is staged entirely in LDS first. 1024 blocks x
// 256 thr, 4096 pts/block = 32 KB LDS -> whole grid resident (4 blocks/CU),
// so phases align GLOBALLY: Phase 1 = chip-wide pure-read burst into LDS,
// __syncthreads, Phase 2 = compute from LDS + pure-write stream of all
// 184.5 MB (fill-shaped; no reads anywhere during it). Store shapes
// identical to v1 (never the problem). LDS access lane-contiguous f2v =
// 2 lanes/bank = conflict-free.

typedef float f2v __attribute__((ext_vector_type(2)));
typedef float f4v __attribute__((ext_vector_type(4)));

#define BLOCK 256
#define PTS_PER_BLOCK 4096            // 32 KB input slice per block
#define ITERS (PTS_PER_BLOCK / BLOCK) // 16

__global__ __launch_bounds__(BLOCK) void fw_phased_kernel(
    const f2v* __restrict__ in, float* __restrict__ out, int n) {
    __shared__ f2v smem[PTS_PER_BLOCK];   // 4096 points = 32 KB

    const float BETA = 0.1f;
    int t = threadIdx.x;
    size_t N = (size_t)n;
    size_t base = (size_t)blockIdx.x * PTS_PER_BLOCK;

    // ---- Phase 1: pure-read burst (global -> LDS) ----
    #pragma unroll
    for (int k = 0; k < ITERS; ++k) {
        size_t idx = base + (size_t)(t + k * BLOCK);
        if (idx < N) smem[t + k * BLOCK] = in[idx];
    }
    __syncthreads();

    // ---- Phase 2: compute from LDS, pure-write stream ----
    float* e_out  = out;
    f2v*   f_out  = (f2v*)(out + N);
    f2v*   g_out  = (f2v*)(out + 3 * N);
    f4v*   h_out  = (f4v*)(out + 5 * N);
    float* l0_out = out + 9 * N;
    float* l1_out = out + 10 * N;

    #pragma unroll 4
    for (int k = 0; k < ITERS; ++k) {
        int p = t + k * BLOCK;               // 0..4095, lane-contiguous
        size_t i = base + (size_t)p;
        if (i < N) {
            f2v pt = smem[p];                // ds_read_b64, conflict-free

            float u = pt.x - 0.5f;
            float v = pt.y - 0.5f;
            float uu = u * u;
            float vv = v * v;
            float a = uu - 1.0f;             // u^2 - 1
            float b = vv - 1.0f;             // v^2 - 1

            float energy = a * a + b * b + BETA * u * v;

            float gx = 4.0f * u * a + BETA * v;
            float gy = 4.0f * v * b + BETA * u;
            float fx = -gx;
            float fy = -gy;

            float hxx = 12.0f * uu - 4.0f;
            float hyy = 12.0f * vv - 4.0f;
            // hxy = BETA (constant)

            // 2x2 symmetric eigendecomposition, closed form.
            float d = 0.5f * (hxx - hyy);
            float m = 0.5f * (hxx + hyy);
            float r = __builtin_amdgcn_sqrtf(d * d + BETA * BETA); // >= 0.1
            float l0 = m - r;                // smaller eigenvalue
            float l1 = m + r;                // larger eigenvalue

            // Eigenvector of l0; select-branch avoids fp32 cancellation
            // (|d| up to ~380 vs hxy=0.1; wrong branch computes r-|d|).
            bool pos = (d >= 0.0f);
            float wx = pos ? BETA : (d - r);
            float wy = pos ? -(d + r) : BETA;
            float n2 = wx * wx + wy * wy;    // >= 0.01

            // gad = -f + 2 (f.w_hat) w_hat ; sign of w irrelevant.
            float fd = fx * wx + fy * wy;
            float s = (2.0f * fd) * __builtin_amdgcn_rcpf(n2);
            float gadx = -fx + s * wx;
            float gady = -fy + s * wy;

            float prod = l0 * l1;            // reference's eigval product
            float g2 = gadx * gadx + gady * gady;  // gmag<1 <=> g2<1
            if (prod > 0.0f && g2 < 1.0f) {
                float inv = __builtin_amdgcn_rsqf(fmaxf(g2, 1e-60f));
                gadx *= inv;
                gady *= inv;
            }
            // TAU = 1.0 -> energy_grad == gad

            e_out[i] = energy;
            f2v fo; fo.x = fx; fo.y = fy;
            f_out[i] = fo;
            f2v go; go.x = gadx; go.y = gady;
            g_out[i] = go;
            f4v ho; ho.x = hxx; ho.y = BETA; ho.z = BETA; ho.w = hyy;
            h_out[i] = ho;
            l0_out[i] = l0;
            l1_out[i] = l1;
        }
    }
}

extern "C" void kernel_launch(void* const* d_in, const int* in_sizes, int n_in,
                              void* d_out, int out_size, void* d_ws, size_t ws_size,
                              hipStream_t stream) {
    const f2v* in = (const f2v*)d_in[0];
    float* out = (float*)d_out;
    int n = in_sizes[0] / 2;   // B points, each (x, y)

    int grid = (n + PTS_PER_BLOCK - 1) / PTS_PER_BLOCK;  // 1024 for B
    if (grid < 1) grid = 1;
    fw_phased_kernel<<<grid, BLOCK, 0, stream>>>(in, out, n);
}